// Round 6
// baseline (215.610 us; speedup 1.0000x reference)
//
#include <hip/hip_runtime.h>
#include <hip/hip_bf16.h>
#include <cstdint>

#define D_MODEL 128
#define N_HEADS 8
#define HEAD_DIM 16

typedef __attribute__((ext_vector_type(8))) short bf16x8;
typedef __attribute__((ext_vector_type(4))) float f32x4;

static __device__ __forceinline__ float b2f(unsigned short u) {
  unsigned int x = ((unsigned int)u) << 16;
  return __builtin_bit_cast(float, x);
}
static __device__ __forceinline__ unsigned short f2b(float f) {
  __hip_bfloat16 h = __float2bfloat16(f);   // RNE
  return __builtin_bit_cast(unsigned short, h);
}

// ---------------------------------------------------------------------------
// fp32 -> bf16 conversion of the three 128x128 W matrices only (tiny).
// ---------------------------------------------------------------------------
__global__ __launch_bounds__(256) void cvtw_kernel(
    const float* __restrict__ Wq, const float* __restrict__ Wk,
    const float* __restrict__ Wv, unsigned short* __restrict__ Wb)
{
  const int wb = blockIdx.x;           // 24 blocks: 8 per matrix
  const int m  = wb >> 3;
  const float* src = (m == 0) ? Wq : (m == 1) ? Wk : Wv;
  unsigned short* dst = Wb + (size_t)m * 16384;
  const int base = ((wb & 7) * 256 + threadIdx.x) * 8;
  const float4 a = reinterpret_cast<const float4*>(src + base)[0];
  const float4 c = reinterpret_cast<const float4*>(src + base)[1];
  unsigned short tmp[8];
  tmp[0] = f2b(a.x); tmp[1] = f2b(a.y); tmp[2] = f2b(a.z); tmp[3] = f2b(a.w);
  tmp[4] = f2b(c.x); tmp[5] = f2b(c.y); tmp[6] = f2b(c.z); tmp[7] = f2b(c.w);
  reinterpret_cast<uint4*>(dst + base)[0] = *reinterpret_cast<uint4*>(tmp);
}

// ---------------------------------------------------------------------------
// MFMA QKV: O[n][j] = sum_k X[n][k] * W[j][k] + b[j].
// X read as fp32, converted in-register to the bf16 A-fragment.
// ---------------------------------------------------------------------------
__global__ __launch_bounds__(256) void qkv_mfma(
    const float* __restrict__ X, const unsigned short* __restrict__ Wb,
    const float* __restrict__ bq, const float* __restrict__ bk,
    const float* __restrict__ bv,
    unsigned short* __restrict__ Qo, unsigned short* __restrict__ Ko,
    unsigned short* __restrict__ Vo, int N)
{
  const int wave = threadIdx.x >> 6;
  const int l    = threadIdx.x & 63;
  const int tile = blockIdx.x * 4 + wave;
  const int n0   = tile * 16;
  if (n0 >= N) return;
  const int lr = l & 15;
  const int lg = l >> 4;

  bf16x8 a[4];
  const int arow = n0 + lr;
  if (arow < N) {
    const float* xp = X + (size_t)arow * D_MODEL + lg * 8;
    #pragma unroll
    for (int ks = 0; ks < 4; ++ks) {
      const float4 f0 = reinterpret_cast<const float4*>(xp + ks * 32)[0];
      const float4 f1 = reinterpret_cast<const float4*>(xp + ks * 32)[1];
      unsigned short t[8];
      t[0] = f2b(f0.x); t[1] = f2b(f0.y); t[2] = f2b(f0.z); t[3] = f2b(f0.w);
      t[4] = f2b(f1.x); t[5] = f2b(f1.y); t[6] = f2b(f1.z); t[7] = f2b(f1.w);
      a[ks] = *reinterpret_cast<bf16x8*>(t);
    }
  } else {
    #pragma unroll
    for (int ks = 0; ks < 4; ++ks) a[ks] = bf16x8{0,0,0,0,0,0,0,0};
  }

  const float* biases[3] = {bq, bk, bv};
  unsigned short* outs[3] = {Qo, Ko, Vo};

  #pragma unroll 1
  for (int m = 0; m < 3; ++m) {
    const unsigned short* __restrict__ W = Wb + (size_t)m * 16384;
    unsigned short* __restrict__ O = outs[m];
    const float* __restrict__ bias = biases[m];
    #pragma unroll 1
    for (int c = 0; c < 8; ++c) {
      const float bj = bias[c * 16 + lr];
      f32x4 acc = {bj, bj, bj, bj};
      const unsigned short* wp = W + (size_t)(c * 16 + lr) * D_MODEL + lg * 8;
      #pragma unroll
      for (int ks = 0; ks < 4; ++ks) {
        const bf16x8 bfr = *reinterpret_cast<const bf16x8*>(wp + ks * 32);
        acc = __builtin_amdgcn_mfma_f32_16x16x32_bf16(a[ks], bfr, acc, 0, 0, 0);
      }
      #pragma unroll
      for (int r = 0; r < 4; ++r) {
        const int orow = n0 + lg * 4 + r;
        if (orow < N) O[(size_t)orow * D_MODEL + c * 16 + lr] = f2b(acc[r]);
      }
    }
  }
}

// ---------------------------------------------------------------------------
// CSR build: histogram -> hierarchical scan -> scatter
// ---------------------------------------------------------------------------
__global__ __launch_bounds__(256) void hist_kernel(
    const int* __restrict__ rows, int* __restrict__ cnt, int E)
{
  const int e = blockIdx.x * 256 + threadIdx.x;
  if (e < E) atomicAdd(&cnt[rows[e]], 1);
}

__global__ __launch_bounds__(256) void partial_kernel(
    const int* __restrict__ cnt, int* __restrict__ bsum, int N)
{
  __shared__ int wsum[4];
  const int t = threadIdx.x;
  const int base = blockIdx.x * 1024 + t * 4;
  int s = 0;
  #pragma unroll
  for (int i = 0; i < 4; ++i)
    if (base + i < N) s += cnt[base + i];
  #pragma unroll
  for (int off = 32; off > 0; off >>= 1) s += __shfl_xor(s, off, 64);
  if ((t & 63) == 0) wsum[t >> 6] = s;
  __syncthreads();
  if (t == 0) bsum[blockIdx.x] = wsum[0] + wsum[1] + wsum[2] + wsum[3];
}

__global__ __launch_bounds__(256) void scansums_kernel(
    const int* __restrict__ bsum, int* __restrict__ boff, int nb)
{
  __shared__ int p[256];
  __shared__ int carry_s;
  const int t = threadIdx.x;
  if (t == 0) carry_s = 0;
  __syncthreads();
  for (int c0 = 0; c0 < nb; c0 += 256) {
    const int v = (c0 + t < nb) ? bsum[c0 + t] : 0;
    p[t] = v;
    __syncthreads();
    for (int off = 1; off < 256; off <<= 1) {
      const int other = (t >= off) ? p[t - off] : 0;
      __syncthreads();
      p[t] += other;
      __syncthreads();
    }
    const int carry = carry_s;
    if (c0 + t < nb) boff[c0 + t] = carry + p[t] - v;
    __syncthreads();
    if (t == 0) carry_s = carry + p[255];
    __syncthreads();
  }
}

__global__ __launch_bounds__(256) void emit_kernel(
    const int* __restrict__ cnt, const int* __restrict__ boff,
    int* __restrict__ row_ptr, int* __restrict__ row_cur, int N, int E)
{
  __shared__ int psum[256];
  const int t = threadIdx.x;
  const int base = blockIdx.x * 1024 + t * 4;
  int v[4];
  #pragma unroll
  for (int i = 0; i < 4; ++i)
    v[i] = (base + i < N) ? cnt[base + i] : 0;
  const int local = v[0] + v[1] + v[2] + v[3];
  psum[t] = local;
  __syncthreads();
  for (int off = 1; off < 256; off <<= 1) {
    const int other = (t >= off) ? psum[t - off] : 0;
    __syncthreads();
    psum[t] += other;
    __syncthreads();
  }
  int pre = boff[blockIdx.x] + psum[t] - local;
  #pragma unroll
  for (int i = 0; i < 4; ++i) {
    const int idx = base + i;
    if (idx < N) {
      row_ptr[idx] = pre;
      row_cur[idx] = pre;
      pre += v[i];
    }
  }
  if (blockIdx.x == 0 && t == 0) row_ptr[N] = E;
}

__global__ __launch_bounds__(256) void scatter_kernel(
    const int* __restrict__ rows, const int* __restrict__ cols,
    int* __restrict__ row_cur, int* __restrict__ csr_cols, int E)
{
  const int e = blockIdx.x * 256 + threadIdx.x;
  if (e >= E) return;
  const int pos = atomicAdd(&row_cur[rows[e]], 1);
  csr_cols[pos] = cols[e];
}

// ---------------------------------------------------------------------------
// Fused per-node attention + residual + LayerNorm. bf16 Q/K/V, fp32 math.
// One wave per node, edges in chunks of 8. Phase 2 is fully unconditional:
// invalid slots carry ea=0 / c=0 (row-0 gather hits cache, adds zero), so all
// 8 V-row gathers are independent and pipeline without control dependence.
// ---------------------------------------------------------------------------
__global__ __launch_bounds__(256) void fused_kernel(
    const unsigned short* __restrict__ Q, const unsigned short* __restrict__ K,
    const unsigned short* __restrict__ V, const float* __restrict__ X,
    const int* __restrict__ row_ptr, const int* __restrict__ csr_cols,
    const float* __restrict__ gamma, const float* __restrict__ beta,
    float* __restrict__ out, int N)
{
  const int n = blockIdx.x * 4 + (threadIdx.x >> 6);
  if (n >= N) return;
  const int l  = threadIdx.x & 63;
  const int h  = l & 7;    // phase-1 head
  const int g  = l >> 3;   // phase-1 edge slot
  const int hd = l >> 3;   // phase-2 head owning dims {2l, 2l+1}

  float qf[16];
  {
    const unsigned short* qp = Q + (size_t)n * D_MODEL + h * HEAD_DIM;
    const bf16x8 q0 = *reinterpret_cast<const bf16x8*>(qp);
    const bf16x8 q1 = *reinterpret_cast<const bf16x8*>(qp + 8);
    #pragma unroll
    for (int i = 0; i < 8; ++i) {
      qf[i]     = b2f((unsigned short)q0[i]);
      qf[8 + i] = b2f((unsigned short)q1[i]);
    }
  }

  float accx = 0.f, accy = 0.f, dlane = 0.f;
  const int e0 = row_ptr[n];
  const int e1 = row_ptr[n + 1];

  for (int eb = e0; eb < e1; eb += 8) {
    // ---- phase 1: scores for 8 edges (lane g = edge slot, lane h = head) ----
    const int  eg    = eb + g;
    const bool valid = eg < e1;
    const int  c     = valid ? csr_cols[eg] : 0;

    const unsigned short* kp = K + (size_t)c * D_MODEL + h * HEAD_DIM;
    const bf16x8 k0 = *reinterpret_cast<const bf16x8*>(kp);
    const bf16x8 k1 = *reinterpret_cast<const bf16x8*>(kp + 8);
    float s = 0.f;
    #pragma unroll
    for (int i = 0; i < 8; ++i) {
      s = fmaf(qf[i],     b2f((unsigned short)k0[i]), s);
      s = fmaf(qf[8 + i], b2f((unsigned short)k1[i]), s);
    }
    s *= 0.25f;                         // 1/sqrt(16)
    s = fminf(fmaxf(s, -10.f), 10.f);
    const float ea = valid ? __expf(s) : 0.f;
    dlane += ea;

    // ---- phase 2: broadcast all 8 (c, ea), then 8 independent V gathers ----
    float aj[8];
    int   cj[8];
    #pragma unroll
    for (int j = 0; j < 8; ++j) {
      const int src = j * 8 + hd;
      aj[j] = __shfl(ea, src, 64);
      cj[j] = __shfl(c,  src, 64);
    }
    #pragma unroll
    for (int j = 0; j < 8; ++j) {
      const ushort2 vu = reinterpret_cast<const ushort2*>(V + (size_t)cj[j] * D_MODEL)[l];
      accx = fmaf(aj[j], b2f(vu.x), accx);
      accy = fmaf(aj[j], b2f(vu.y), accy);
    }
  }

  // denominator: sum over the 8 g-lanes sharing head h (bits 3,4,5)
  dlane += __shfl_xor(dlane, 8,  64);
  dlane += __shfl_xor(dlane, 16, 64);
  dlane += __shfl_xor(dlane, 32, 64);
  const float denom = __shfl(dlane, hd, 64);   // lane hd holds head h=hd

  const float inv = 1.f / (denom + 1e-8f);
  const float2 x = reinterpret_cast<const float2*>(X + (size_t)n * D_MODEL)[l];
  const float a0 = accx * inv + x.x;
  const float a1 = accy * inv + x.y;

  float sm = a0 + a1;
  float ss = a0 * a0 + a1 * a1;
  #pragma unroll
  for (int off = 32; off > 0; off >>= 1) {
    sm += __shfl_xor(sm, off, 64);
    ss += __shfl_xor(ss, off, 64);
  }
  const float mean = sm * (1.f / 128.f);
  const float var  = ss * (1.f / 128.f) - mean * mean;
  const float rs   = rsqrtf(var + 1e-6f);
  const float2 gm = reinterpret_cast<const float2*>(gamma)[l];
  const float2 bt = reinterpret_cast<const float2*>(beta)[l];
  float2 o;
  o.x = (a0 - mean) * rs * gm.x + bt.x;
  o.y = (a1 - mean) * rs * gm.y + bt.y;
  reinterpret_cast<float2*>(out + (size_t)n * D_MODEL)[l] = o;
}

// ---------------------------------------------------------------------------
extern "C" void kernel_launch(void* const* d_in, const int* in_sizes, int n_in,
                              void* d_out, int out_size, void* d_ws, size_t ws_size,
                              hipStream_t stream)
{
  const float* X     = (const float*)d_in[0];
  const int*   ei    = (const int*)  d_in[1];
  const float* Wq    = (const float*)d_in[2];
  const float* bq    = (const float*)d_in[3];
  const float* Wk    = (const float*)d_in[4];
  const float* bk    = (const float*)d_in[5];
  const float* Wv    = (const float*)d_in[6];
  const float* bv    = (const float*)d_in[7];
  const float* gamma = (const float*)d_in[8];
  const float* beta  = (const float*)d_in[9];

  const int N = in_sizes[0] / D_MODEL;
  const int E = in_sizes[1] / 2;
  const int* rows = ei;
  const int* cols = ei + E;

  const size_t nd = (size_t)N * D_MODEL;
  unsigned short* Wb = (unsigned short*)d_ws;
  unsigned short* Qb = Wb + 3 * 16384;
  unsigned short* Kb = Qb + nd;
  unsigned short* Vb = Kb + nd;
  int* row_cnt  = (int*)(Vb + nd);
  int* row_ptr  = row_cnt + N;
  int* row_cur  = row_ptr + N + 1;
  int* csr_cols = row_cur + N;
  int* bsum     = csr_cols + E;
  int* boff     = bsum + ((N + 1023) / 1024) + 1;

  const int nb = (N + 1023) / 1024;

  hipMemsetAsync(row_cnt, 0, (size_t)N * sizeof(int), stream);

  cvtw_kernel<<<24, 256, 0, stream>>>(Wq, Wk, Wv, Wb);

  hist_kernel<<<(E + 255) / 256, 256, 0, stream>>>(rows, row_cnt, E);
  partial_kernel<<<nb, 256, 0, stream>>>(row_cnt, bsum, N);
  scansums_kernel<<<1, 256, 0, stream>>>(bsum, boff, nb);
  emit_kernel<<<nb, 256, 0, stream>>>(row_cnt, boff, row_ptr, row_cur, N, E);
  scatter_kernel<<<(E + 255) / 256, 256, 0, stream>>>(rows, cols, row_cur, csr_cols, E);

  qkv_mfma<<<(N / 16 + 4) / 4, 256, 0, stream>>>(
      X, Wb, bq, bk, bv, Qb, Kb, Vb, N);

  fused_kernel<<<(N + 3) / 4, 256, 0, stream>>>(
      Qb, Kb, Vb, X, row_ptr, csr_cols, gamma, beta, (float*)d_out, N);
}

// Round 7
// 191.413 us; speedup vs baseline: 1.1264x; 1.1264x over previous
//
#include <hip/hip_runtime.h>
#include <hip/hip_bf16.h>
#include <cstdint>

#define D_MODEL 128
#define N_HEADS 8
#define HEAD_DIM 16

typedef __attribute__((ext_vector_type(8))) short bf16x8;
typedef __attribute__((ext_vector_type(4))) float f32x4;

static __device__ __forceinline__ float b2f(unsigned short u) {
  unsigned int x = ((unsigned int)u) << 16;
  return __builtin_bit_cast(float, x);
}
static __device__ __forceinline__ unsigned short f2b(float f) {
  __hip_bfloat16 h = __float2bfloat16(f);   // RNE
  return __builtin_bit_cast(unsigned short, h);
}

// ---------------------------------------------------------------------------
// fp32 -> bf16 conversion of the three 128x128 W matrices only (tiny).
// ---------------------------------------------------------------------------
__global__ __launch_bounds__(256) void cvtw_kernel(
    const float* __restrict__ Wq, const float* __restrict__ Wk,
    const float* __restrict__ Wv, unsigned short* __restrict__ Wb)
{
  const int wb = blockIdx.x;           // 24 blocks: 8 per matrix
  const int m  = wb >> 3;
  const float* src = (m == 0) ? Wq : (m == 1) ? Wk : Wv;
  unsigned short* dst = Wb + (size_t)m * 16384;
  const int base = ((wb & 7) * 256 + threadIdx.x) * 8;
  const float4 a = reinterpret_cast<const float4*>(src + base)[0];
  const float4 c = reinterpret_cast<const float4*>(src + base)[1];
  unsigned short tmp[8];
  tmp[0] = f2b(a.x); tmp[1] = f2b(a.y); tmp[2] = f2b(a.z); tmp[3] = f2b(a.w);
  tmp[4] = f2b(c.x); tmp[5] = f2b(c.y); tmp[6] = f2b(c.z); tmp[7] = f2b(c.w);
  reinterpret_cast<uint4*>(dst + base)[0] = *reinterpret_cast<uint4*>(tmp);
}

// ---------------------------------------------------------------------------
// MFMA QKV: O[n][j] = sum_k X[n][k] * W[j][k] + b[j].
// X read as fp32, converted in-register to the bf16 A-fragment.
// ---------------------------------------------------------------------------
__global__ __launch_bounds__(256) void qkv_mfma(
    const float* __restrict__ X, const unsigned short* __restrict__ Wb,
    const float* __restrict__ bq, const float* __restrict__ bk,
    const float* __restrict__ bv,
    unsigned short* __restrict__ Qo, unsigned short* __restrict__ Ko,
    unsigned short* __restrict__ Vo, int N)
{
  const int wave = threadIdx.x >> 6;
  const int l    = threadIdx.x & 63;
  const int tile = blockIdx.x * 4 + wave;
  const int n0   = tile * 16;
  if (n0 >= N) return;
  const int lr = l & 15;
  const int lg = l >> 4;

  bf16x8 a[4];
  const int arow = n0 + lr;
  if (arow < N) {
    const float* xp = X + (size_t)arow * D_MODEL + lg * 8;
    #pragma unroll
    for (int ks = 0; ks < 4; ++ks) {
      const float4 f0 = reinterpret_cast<const float4*>(xp + ks * 32)[0];
      const float4 f1 = reinterpret_cast<const float4*>(xp + ks * 32)[1];
      unsigned short t[8];
      t[0] = f2b(f0.x); t[1] = f2b(f0.y); t[2] = f2b(f0.z); t[3] = f2b(f0.w);
      t[4] = f2b(f1.x); t[5] = f2b(f1.y); t[6] = f2b(f1.z); t[7] = f2b(f1.w);
      a[ks] = *reinterpret_cast<bf16x8*>(t);
    }
  } else {
    #pragma unroll
    for (int ks = 0; ks < 4; ++ks) a[ks] = bf16x8{0,0,0,0,0,0,0,0};
  }

  const float* biases[3] = {bq, bk, bv};
  unsigned short* outs[3] = {Qo, Ko, Vo};

  #pragma unroll 1
  for (int m = 0; m < 3; ++m) {
    const unsigned short* __restrict__ W = Wb + (size_t)m * 16384;
    unsigned short* __restrict__ O = outs[m];
    const float* __restrict__ bias = biases[m];
    #pragma unroll 1
    for (int c = 0; c < 8; ++c) {
      const float bj = bias[c * 16 + lr];
      f32x4 acc = {bj, bj, bj, bj};
      const unsigned short* wp = W + (size_t)(c * 16 + lr) * D_MODEL + lg * 8;
      #pragma unroll
      for (int ks = 0; ks < 4; ++ks) {
        const bf16x8 bfr = *reinterpret_cast<const bf16x8*>(wp + ks * 32);
        acc = __builtin_amdgcn_mfma_f32_16x16x32_bf16(a[ks], bfr, acc, 0, 0, 0);
      }
      #pragma unroll
      for (int r = 0; r < 4; ++r) {
        const int orow = n0 + lg * 4 + r;
        if (orow < N) O[(size_t)orow * D_MODEL + c * 16 + lr] = f2b(acc[r]);
      }
    }
  }
}

// ---------------------------------------------------------------------------
// CSR build: histogram -> hierarchical scan -> scatter
// ---------------------------------------------------------------------------
__global__ __launch_bounds__(256) void hist_kernel(
    const int* __restrict__ rows, int* __restrict__ cnt, int E)
{
  const int e = blockIdx.x * 256 + threadIdx.x;
  if (e < E) atomicAdd(&cnt[rows[e]], 1);
}

__global__ __launch_bounds__(256) void partial_kernel(
    const int* __restrict__ cnt, int* __restrict__ bsum, int N)
{
  __shared__ int wsum[4];
  const int t = threadIdx.x;
  const int base = blockIdx.x * 1024 + t * 4;
  int s = 0;
  #pragma unroll
  for (int i = 0; i < 4; ++i)
    if (base + i < N) s += cnt[base + i];
  #pragma unroll
  for (int off = 32; off > 0; off >>= 1) s += __shfl_xor(s, off, 64);
  if ((t & 63) == 0) wsum[t >> 6] = s;
  __syncthreads();
  if (t == 0) bsum[blockIdx.x] = wsum[0] + wsum[1] + wsum[2] + wsum[3];
}

__global__ __launch_bounds__(256) void scansums_kernel(
    const int* __restrict__ bsum, int* __restrict__ boff, int nb)
{
  __shared__ int p[256];
  __shared__ int carry_s;
  const int t = threadIdx.x;
  if (t == 0) carry_s = 0;
  __syncthreads();
  for (int c0 = 0; c0 < nb; c0 += 256) {
    const int v = (c0 + t < nb) ? bsum[c0 + t] : 0;
    p[t] = v;
    __syncthreads();
    for (int off = 1; off < 256; off <<= 1) {
      const int other = (t >= off) ? p[t - off] : 0;
      __syncthreads();
      p[t] += other;
      __syncthreads();
    }
    const int carry = carry_s;
    if (c0 + t < nb) boff[c0 + t] = carry + p[t] - v;
    __syncthreads();
    if (t == 0) carry_s = carry + p[255];
    __syncthreads();
  }
}

__global__ __launch_bounds__(256) void emit_kernel(
    const int* __restrict__ cnt, const int* __restrict__ boff,
    int* __restrict__ row_ptr, int* __restrict__ row_cur, int N, int E)
{
  __shared__ int psum[256];
  const int t = threadIdx.x;
  const int base = blockIdx.x * 1024 + t * 4;
  int v[4];
  #pragma unroll
  for (int i = 0; i < 4; ++i)
    v[i] = (base + i < N) ? cnt[base + i] : 0;
  const int local = v[0] + v[1] + v[2] + v[3];
  psum[t] = local;
  __syncthreads();
  for (int off = 1; off < 256; off <<= 1) {
    const int other = (t >= off) ? psum[t - off] : 0;
    __syncthreads();
    psum[t] += other;
    __syncthreads();
  }
  int pre = boff[blockIdx.x] + psum[t] - local;
  #pragma unroll
  for (int i = 0; i < 4; ++i) {
    const int idx = base + i;
    if (idx < N) {
      row_ptr[idx] = pre;
      row_cur[idx] = pre;
      pre += v[i];
    }
  }
  if (blockIdx.x == 0 && t == 0) row_ptr[N] = E;
}

__global__ __launch_bounds__(256) void scatter_kernel(
    const int* __restrict__ rows, const int* __restrict__ cols,
    int* __restrict__ row_cur, int* __restrict__ csr_cols, int E)
{
  const int e = blockIdx.x * 256 + threadIdx.x;
  if (e >= E) return;
  const int pos = atomicAdd(&row_cur[rows[e]], 1);
  csr_cols[pos] = cols[e];
}

// ---------------------------------------------------------------------------
// Fused per-node attention + residual + LayerNorm. bf16 Q/K/V, fp32 math.
// One wave per node, edges in chunks of 8.
// Phase 1: lane (g = l>>3 edge slot, h = l&7 head) loads K[c_g] AND V[c_g]
//          head-h slices (2 independent 2x16B loads), computes the 16-wide
//          dot in-lane, stages V + ea to LDS (rotation-swizzled, <=2 way).
// Phase 2: lane owns output dims {2l,2l+1}; per edge slot j it reads ea and
//          the V dword from LDS — NO global loads, NO bpermutes.
// Per chunk only 2 dependent global latencies (csr_cols, then K||V).
// ---------------------------------------------------------------------------
__global__ __launch_bounds__(256) void fused_kernel(
    const unsigned short* __restrict__ Q, const unsigned short* __restrict__ K,
    const unsigned short* __restrict__ V, const float* __restrict__ X,
    const int* __restrict__ row_ptr, const int* __restrict__ csr_cols,
    const float* __restrict__ gamma, const float* __restrict__ beta,
    float* __restrict__ out, int N)
{
  __shared__ float lds[4][576];          // per wave: 512 V dwords + 64 ea
  const int wv = threadIdx.x >> 6;
  const int n  = blockIdx.x * 4 + wv;
  if (n >= N) return;
  const int l  = threadIdx.x & 63;
  const int h  = l & 7;    // phase-1 head
  const int g  = l >> 3;   // phase-1 edge slot
  const int hd = l >> 3;   // phase-2 head owning dims {2l, 2l+1}

  unsigned* __restrict__ Vu = reinterpret_cast<unsigned*>(lds[wv]);
  float*    __restrict__ El = lds[wv] + 512;

  float qf[16];
  {
    const unsigned short* qp = Q + (size_t)n * D_MODEL + h * HEAD_DIM;
    const bf16x8 q0 = *reinterpret_cast<const bf16x8*>(qp);
    const bf16x8 q1 = *reinterpret_cast<const bf16x8*>(qp + 8);
    #pragma unroll
    for (int i = 0; i < 8; ++i) {
      qf[i]     = b2f((unsigned short)q0[i]);
      qf[8 + i] = b2f((unsigned short)q1[i]);
    }
  }

  float accx = 0.f, accy = 0.f, dlane = 0.f;
  const int e0 = row_ptr[n];
  const int e1 = row_ptr[n + 1];

  // phase-2 read offsets (compile-time foldable)
  const int rcol = (l & 7) * 64;
  const int rrot = (l >> 3) + 4 * (l & 7);

  for (int eb = e0; eb < e1; eb += 8) {
    // ---- phase 1: scores + V staging for 8 edges ----
    const int  eg    = eb + g;
    const bool valid = eg < e1;
    const int  c     = valid ? csr_cols[eg] : 0;

    const unsigned short* kp = K + (size_t)c * D_MODEL + h * HEAD_DIM;
    const unsigned short* vp = V + (size_t)c * D_MODEL + h * HEAD_DIM;
    const bf16x8 k0 = *reinterpret_cast<const bf16x8*>(kp);
    const bf16x8 k1 = *reinterpret_cast<const bf16x8*>(kp + 8);
    const bf16x8 v0 = *reinterpret_cast<const bf16x8*>(vp);
    const bf16x8 v1 = *reinterpret_cast<const bf16x8*>(vp + 8);

    float s = 0.f;
    #pragma unroll
    for (int i = 0; i < 8; ++i) {
      s = fmaf(qf[i],     b2f((unsigned short)k0[i]), s);
      s = fmaf(qf[8 + i], b2f((unsigned short)k1[i]), s);
    }
    s *= 0.25f;                         // 1/sqrt(16)
    s = fminf(fmaxf(s, -10.f), 10.f);
    const float ea = valid ? __expf(s) : 0.f;
    dlane += ea;

    // stage ea + V slice to LDS (rotation swizzle: write banks (l+4i)%32)
    El[l] = ea;
    {
      const uint4 u0 = __builtin_bit_cast(uint4, v0);
      const uint4 u1 = __builtin_bit_cast(uint4, v1);
      Vu[0 * 64 + ((l +  0) & 63)] = u0.x;
      Vu[1 * 64 + ((l +  4) & 63)] = u0.y;
      Vu[2 * 64 + ((l +  8) & 63)] = u0.z;
      Vu[3 * 64 + ((l + 12) & 63)] = u0.w;
      Vu[4 * 64 + ((l + 16) & 63)] = u1.x;
      Vu[5 * 64 + ((l + 20) & 63)] = u1.y;
      Vu[6 * 64 + ((l + 24) & 63)] = u1.z;
      Vu[7 * 64 + ((l + 28) & 63)] = u1.w;
    }
    __builtin_amdgcn_sched_barrier(0);   // writes before reads (same-wave RAW)

    // ---- phase 2: pure-LDS accumulation over the 8 edge slots ----
    #pragma unroll
    for (int j = 0; j < 8; ++j) {
      const float    aj = El[j * 8 + hd];
      const unsigned vv = Vu[rcol + ((j * 8 + rrot) & 63)];
      accx = fmaf(aj, b2f((unsigned short)(vv & 0xffffu)), accx);
      accy = fmaf(aj, b2f((unsigned short)(vv >> 16)), accy);
    }
    __builtin_amdgcn_sched_barrier(0);   // reads before next chunk's writes
  }

  // denominator: sum over the 8 g-lanes sharing head h (bits 3,4,5)
  dlane += __shfl_xor(dlane, 8,  64);
  dlane += __shfl_xor(dlane, 16, 64);
  dlane += __shfl_xor(dlane, 32, 64);
  const float denom = __shfl(dlane, hd, 64);   // lane hd holds head h=hd

  const float inv = 1.f / (denom + 1e-8f);
  const float2 x = reinterpret_cast<const float2*>(X + (size_t)n * D_MODEL)[l];
  const float a0 = accx * inv + x.x;
  const float a1 = accy * inv + x.y;

  float sm = a0 + a1;
  float ss = a0 * a0 + a1 * a1;
  #pragma unroll
  for (int off = 32; off > 0; off >>= 1) {
    sm += __shfl_xor(sm, off, 64);
    ss += __shfl_xor(ss, off, 64);
  }
  const float mean = sm * (1.f / 128.f);
  const float var  = ss * (1.f / 128.f) - mean * mean;
  const float rs   = rsqrtf(var + 1e-6f);
  const float2 gm = reinterpret_cast<const float2*>(gamma)[l];
  const float2 bt = reinterpret_cast<const float2*>(beta)[l];
  float2 o;
  o.x = (a0 - mean) * rs * gm.x + bt.x;
  o.y = (a1 - mean) * rs * gm.y + bt.y;
  reinterpret_cast<float2*>(out + (size_t)n * D_MODEL)[l] = o;
}

// ---------------------------------------------------------------------------
extern "C" void kernel_launch(void* const* d_in, const int* in_sizes, int n_in,
                              void* d_out, int out_size, void* d_ws, size_t ws_size,
                              hipStream_t stream)
{
  const float* X     = (const float*)d_in[0];
  const int*   ei    = (const int*)  d_in[1];
  const float* Wq    = (const float*)d_in[2];
  const float* bq    = (const float*)d_in[3];
  const float* Wk    = (const float*)d_in[4];
  const float* bk    = (const float*)d_in[5];
  const float* Wv    = (const float*)d_in[6];
  const float* bv    = (const float*)d_in[7];
  const float* gamma = (const float*)d_in[8];
  const float* beta  = (const float*)d_in[9];

  const int N = in_sizes[0] / D_MODEL;
  const int E = in_sizes[1] / 2;
  const int* rows = ei;
  const int* cols = ei + E;

  const size_t nd = (size_t)N * D_MODEL;
  unsigned short* Wb = (unsigned short*)d_ws;
  unsigned short* Qb = Wb + 3 * 16384;
  unsigned short* Kb = Qb + nd;
  unsigned short* Vb = Kb + nd;
  int* row_cnt  = (int*)(Vb + nd);
  int* row_ptr  = row_cnt + N;
  int* row_cur  = row_ptr + N + 1;
  int* csr_cols = row_cur + N;
  int* bsum     = csr_cols + E;
  int* boff     = bsum + ((N + 1023) / 1024) + 1;

  const int nb = (N + 1023) / 1024;

  hipMemsetAsync(row_cnt, 0, (size_t)N * sizeof(int), stream);

  cvtw_kernel<<<24, 256, 0, stream>>>(Wq, Wk, Wv, Wb);

  hist_kernel<<<(E + 255) / 256, 256, 0, stream>>>(rows, row_cnt, E);
  partial_kernel<<<nb, 256, 0, stream>>>(row_cnt, bsum, N);
  scansums_kernel<<<1, 256, 0, stream>>>(bsum, boff, nb);
  emit_kernel<<<nb, 256, 0, stream>>>(row_cnt, boff, row_ptr, row_cur, N, E);
  scatter_kernel<<<(E + 255) / 256, 256, 0, stream>>>(rows, cols, row_cur, csr_cols, E);

  qkv_mfma<<<(N / 16 + 4) / 4, 256, 0, stream>>>(
      X, Wb, bq, bk, bv, Qb, Kb, Vb, N);

  fused_kernel<<<(N + 3) / 4, 256, 0, stream>>>(
      Qb, Kb, Vb, X, row_ptr, csr_cols, gamma, beta, (float*)d_out, N);
}

// Round 9
// 164.016 us; speedup vs baseline: 1.3146x; 1.1670x over previous
//
#include <hip/hip_runtime.h>
#include <hip/hip_bf16.h>
#include <cstdint>

#define D_MODEL 128
#define N_HEADS 8
#define HEAD_DIM 16

typedef __attribute__((ext_vector_type(8))) short bf16x8;
typedef __attribute__((ext_vector_type(4))) float f32x4;

static __device__ __forceinline__ float b2f(unsigned short u) {
  unsigned int x = ((unsigned int)u) << 16;
  return __builtin_bit_cast(float, x);
}
static __device__ __forceinline__ unsigned short f2b(float f) {
  __hip_bfloat16 h = __float2bfloat16(f);   // RNE
  return __builtin_bit_cast(unsigned short, h);
}

// ---------------------------------------------------------------------------
// fp32 -> bf16 conversion of the three 128x128 W matrices only (tiny).
// ---------------------------------------------------------------------------
__global__ __launch_bounds__(256) void cvtw_kernel(
    const float* __restrict__ Wq, const float* __restrict__ Wk,
    const float* __restrict__ Wv, unsigned short* __restrict__ Wb)
{
  const int wb = blockIdx.x;           // 24 blocks: 8 per matrix
  const int m  = wb >> 3;
  const float* src = (m == 0) ? Wq : (m == 1) ? Wk : Wv;
  unsigned short* dst = Wb + (size_t)m * 16384;
  const int base = ((wb & 7) * 256 + threadIdx.x) * 8;
  const float4 a = reinterpret_cast<const float4*>(src + base)[0];
  const float4 c = reinterpret_cast<const float4*>(src + base)[1];
  unsigned short tmp[8];
  tmp[0] = f2b(a.x); tmp[1] = f2b(a.y); tmp[2] = f2b(a.z); tmp[3] = f2b(a.w);
  tmp[4] = f2b(c.x); tmp[5] = f2b(c.y); tmp[6] = f2b(c.z); tmp[7] = f2b(c.w);
  reinterpret_cast<uint4*>(dst + base)[0] = *reinterpret_cast<uint4*>(tmp);
}

// ---------------------------------------------------------------------------
// MFMA QKV: O[n][j] = sum_k X[n][k] * W[j][k] + b[j].
// 2 waves/block, 32 nodes/wave (2 x 16-node groups), 64 nodes/block.
// Per m: W staged once into LDS (32 KB = 2048 uint4 chunks; 16 chunks/thread,
// XOR-swizzled, 2-way-aliased conflict-free b128 reads); c-loop fully
// unrolled: 4 ds_read_b128 + 8 MFMAs per c, zero global loads in hot loop.
// ---------------------------------------------------------------------------
__global__ __launch_bounds__(128) void qkv_mfma(
    const float* __restrict__ X, const unsigned short* __restrict__ Wb,
    const float* __restrict__ bq, const float* __restrict__ bk,
    const float* __restrict__ bv,
    unsigned short* __restrict__ Qo, unsigned short* __restrict__ Ko,
    unsigned short* __restrict__ Vo, int N)
{
  __shared__ unsigned short Wl[128 * 128];   // 32 KB, restaged per m
  const int t    = threadIdx.x;
  const int wave = t >> 6;
  const int l    = t & 63;
  const int lr   = l & 15;
  const int lg   = l >> 4;
  const int nw   = blockIdx.x * 64 + wave * 32;   // first node of this wave

  // A fragments: 2 node-groups x 4 k-slices (fp32 load, in-register cvt)
  bf16x8 a[2][4];
  #pragma unroll
  for (int ng = 0; ng < 2; ++ng) {
    const int arow = nw + ng * 16 + lr;
    if (arow < N) {
      const float* xp = X + (size_t)arow * D_MODEL + lg * 8;
      #pragma unroll
      for (int ks = 0; ks < 4; ++ks) {
        const float4 f0 = reinterpret_cast<const float4*>(xp + ks * 32)[0];
        const float4 f1 = reinterpret_cast<const float4*>(xp + ks * 32)[1];
        unsigned short tm[8];
        tm[0] = f2b(f0.x); tm[1] = f2b(f0.y); tm[2] = f2b(f0.z); tm[3] = f2b(f0.w);
        tm[4] = f2b(f1.x); tm[5] = f2b(f1.y); tm[6] = f2b(f1.z); tm[7] = f2b(f1.w);
        a[ng][ks] = *reinterpret_cast<bf16x8*>(tm);
      }
    } else {
      #pragma unroll
      for (int ks = 0; ks < 4; ++ks) a[ng][ks] = bf16x8{0,0,0,0,0,0,0,0};
    }
  }

  const float* biases[3] = {bq, bk, bv};
  unsigned short* outs[3] = {Qo, Ko, Vo};

  #pragma unroll 1
  for (int m = 0; m < 3; ++m) {
    __syncthreads();   // previous m's reads complete before restage
    // stage W[m]: 32768 B = 2048 uint4 chunks; 16 chunks/thread, coalesced
    {
      const uint4* wsrc = reinterpret_cast<const uint4*>(Wb + (size_t)m * 16384);
      uint4* wl4 = reinterpret_cast<uint4*>(Wl);
      #pragma unroll
      for (int i = 0; i < 16; ++i) {
        const int cg = i * 128 + t;          // global chunk id, 0..2047
        const int r  = cg >> 4;              // W row (output col), 0..127
        const int j  = cg & 15;              // 16B chunk within row
        wl4[r * 16 + (j ^ (r & 7))] = wsrc[cg];
      }
    }
    __syncthreads();

    unsigned short* __restrict__ O = outs[m];
    const float* __restrict__ bias = biases[m];
    float bias8[8];
    #pragma unroll
    for (int c = 0; c < 8; ++c) bias8[c] = bias[c * 16 + lr];

    #pragma unroll
    for (int c = 0; c < 8; ++c) {
      const int row = c * 16 + lr;
      bf16x8 w[4];
      #pragma unroll
      for (int ks = 0; ks < 4; ++ks) {
        const int j = ks * 4 + lg;
        w[ks] = *reinterpret_cast<const bf16x8*>(
            Wl + ((row * 16 + (j ^ (row & 7))) * 8));
      }
      #pragma unroll
      for (int ng = 0; ng < 2; ++ng) {
        f32x4 acc = {bias8[c], bias8[c], bias8[c], bias8[c]};
        #pragma unroll
        for (int ks = 0; ks < 4; ++ks)
          acc = __builtin_amdgcn_mfma_f32_16x16x32_bf16(a[ng][ks], w[ks], acc, 0, 0, 0);
        #pragma unroll
        for (int r = 0; r < 4; ++r) {
          const int orow = nw + ng * 16 + lg * 4 + r;
          if (orow < N) O[(size_t)orow * D_MODEL + c * 16 + lr] = f2b(acc[r]);
        }
      }
    }
  }
}

// ---------------------------------------------------------------------------
// CSR build: histogram -> hierarchical scan -> scatter
// ---------------------------------------------------------------------------
__global__ __launch_bounds__(256) void hist_kernel(
    const int* __restrict__ rows, int* __restrict__ cnt, int E)
{
  const int e = blockIdx.x * 256 + threadIdx.x;
  if (e < E) atomicAdd(&cnt[rows[e]], 1);
}

__global__ __launch_bounds__(256) void partial_kernel(
    const int* __restrict__ cnt, int* __restrict__ bsum, int N)
{
  __shared__ int wsum[4];
  const int t = threadIdx.x;
  const int base = blockIdx.x * 1024 + t * 4;
  int s = 0;
  #pragma unroll
  for (int i = 0; i < 4; ++i)
    if (base + i < N) s += cnt[base + i];
  #pragma unroll
  for (int off = 32; off > 0; off >>= 1) s += __shfl_xor(s, off, 64);
  if ((t & 63) == 0) wsum[t >> 6] = s;
  __syncthreads();
  if (t == 0) bsum[blockIdx.x] = wsum[0] + wsum[1] + wsum[2] + wsum[3];
}

__global__ __launch_bounds__(256) void scansums_kernel(
    const int* __restrict__ bsum, int* __restrict__ boff, int nb)
{
  __shared__ int p[256];
  __shared__ int carry_s;
  const int t = threadIdx.x;
  if (t == 0) carry_s = 0;
  __syncthreads();
  for (int c0 = 0; c0 < nb; c0 += 256) {
    const int v = (c0 + t < nb) ? bsum[c0 + t] : 0;
    p[t] = v;
    __syncthreads();
    for (int off = 1; off < 256; off <<= 1) {
      const int other = (t >= off) ? p[t - off] : 0;
      __syncthreads();
      p[t] += other;
      __syncthreads();
    }
    const int carry = carry_s;
    if (c0 + t < nb) boff[c0 + t] = carry + p[t] - v;
    __syncthreads();
    if (t == 0) carry_s = carry + p[255];
    __syncthreads();
  }
}

__global__ __launch_bounds__(256) void emit_kernel(
    const int* __restrict__ cnt, const int* __restrict__ boff,
    int* __restrict__ row_ptr, int* __restrict__ row_cur, int N, int E)
{
  __shared__ int psum[256];
  const int t = threadIdx.x;
  const int base = blockIdx.x * 1024 + t * 4;
  int v[4];
  #pragma unroll
  for (int i = 0; i < 4; ++i)
    v[i] = (base + i < N) ? cnt[base + i] : 0;
  const int local = v[0] + v[1] + v[2] + v[3];
  psum[t] = local;
  __syncthreads();
  for (int off = 1; off < 256; off <<= 1) {
    const int other = (t >= off) ? psum[t - off] : 0;
    __syncthreads();
    psum[t] += other;
    __syncthreads();
  }
  int pre = boff[blockIdx.x] + psum[t] - local;
  #pragma unroll
  for (int i = 0; i < 4; ++i) {
    const int idx = base + i;
    if (idx < N) {
      row_ptr[idx] = pre;
      row_cur[idx] = pre;
      pre += v[i];
    }
  }
  if (blockIdx.x == 0 && t == 0) row_ptr[N] = E;
}

__global__ __launch_bounds__(256) void scatter_kernel(
    const int* __restrict__ rows, const int* __restrict__ cols,
    int* __restrict__ row_cur, int* __restrict__ csr_cols, int E)
{
  const int e = blockIdx.x * 256 + threadIdx.x;
  if (e >= E) return;
  const int pos = atomicAdd(&row_cur[rows[e]], 1);
  csr_cols[pos] = cols[e];
}

// ---------------------------------------------------------------------------
// Fused per-node attention + residual + LayerNorm. bf16 Q/K/V, fp32 math.
// (unchanged from round 6)
// ---------------------------------------------------------------------------
__global__ __launch_bounds__(256) void fused_kernel(
    const unsigned short* __restrict__ Q, const unsigned short* __restrict__ K,
    const unsigned short* __restrict__ V, const float* __restrict__ X,
    const int* __restrict__ row_ptr, const int* __restrict__ csr_cols,
    const float* __restrict__ gamma, const float* __restrict__ beta,
    float* __restrict__ out, int N)
{
  __shared__ float lds[4][576];          // per wave: 512 V dwords + 64 ea
  const int wv = threadIdx.x >> 6;
  const int n  = blockIdx.x * 4 + wv;
  if (n >= N) return;
  const int l  = threadIdx.x & 63;
  const int h  = l & 7;    // phase-1 head
  const int g  = l >> 3;   // phase-1 edge slot
  const int hd = l >> 3;   // phase-2 head owning dims {2l, 2l+1}

  unsigned* __restrict__ Vu = reinterpret_cast<unsigned*>(lds[wv]);
  float*    __restrict__ El = lds[wv] + 512;

  float qf[16];
  {
    const unsigned short* qp = Q + (size_t)n * D_MODEL + h * HEAD_DIM;
    const bf16x8 q0 = *reinterpret_cast<const bf16x8*>(qp);
    const bf16x8 q1 = *reinterpret_cast<const bf16x8*>(qp + 8);
    #pragma unroll
    for (int i = 0; i < 8; ++i) {
      qf[i]     = b2f((unsigned short)q0[i]);
      qf[8 + i] = b2f((unsigned short)q1[i]);
    }
  }

  float accx = 0.f, accy = 0.f, dlane = 0.f;
  const int e0 = row_ptr[n];
  const int e1 = row_ptr[n + 1];

  const int rcol = (l & 7) * 64;
  const int rrot = (l >> 3) + 4 * (l & 7);

  for (int eb = e0; eb < e1; eb += 8) {
    const int  eg    = eb + g;
    const bool valid = eg < e1;
    const int  c     = valid ? csr_cols[eg] : 0;

    const unsigned short* kp = K + (size_t)c * D_MODEL + h * HEAD_DIM;
    const unsigned short* vp = V + (size_t)c * D_MODEL + h * HEAD_DIM;
    const bf16x8 k0 = *reinterpret_cast<const bf16x8*>(kp);
    const bf16x8 k1 = *reinterpret_cast<const bf16x8*>(kp + 8);
    const bf16x8 v0 = *reinterpret_cast<const bf16x8*>(vp);
    const bf16x8 v1 = *reinterpret_cast<const bf16x8*>(vp + 8);

    float s = 0.f;
    #pragma unroll
    for (int i = 0; i < 8; ++i) {
      s = fmaf(qf[i],     b2f((unsigned short)k0[i]), s);
      s = fmaf(qf[8 + i], b2f((unsigned short)k1[i]), s);
    }
    s *= 0.25f;                         // 1/sqrt(16)
    s = fminf(fmaxf(s, -10.f), 10.f);
    const float ea = valid ? __expf(s) : 0.f;
    dlane += ea;

    El[l] = ea;
    {
      const uint4 u0 = __builtin_bit_cast(uint4, v0);
      const uint4 u1 = __builtin_bit_cast(uint4, v1);
      Vu[0 * 64 + ((l +  0) & 63)] = u0.x;
      Vu[1 * 64 + ((l +  4) & 63)] = u0.y;
      Vu[2 * 64 + ((l +  8) & 63)] = u0.z;
      Vu[3 * 64 + ((l + 12) & 63)] = u0.w;
      Vu[4 * 64 + ((l + 16) & 63)] = u1.x;
      Vu[5 * 64 + ((l + 20) & 63)] = u1.y;
      Vu[6 * 64 + ((l + 24) & 63)] = u1.z;
      Vu[7 * 64 + ((l + 28) & 63)] = u1.w;
    }
    __builtin_amdgcn_sched_barrier(0);

    #pragma unroll
    for (int j = 0; j < 8; ++j) {
      const float    aj = El[j * 8 + hd];
      const unsigned vv = Vu[rcol + ((j * 8 + rrot) & 63)];
      accx = fmaf(aj, b2f((unsigned short)(vv & 0xffffu)), accx);
      accy = fmaf(aj, b2f((unsigned short)(vv >> 16)), accy);
    }
    __builtin_amdgcn_sched_barrier(0);
  }

  dlane += __shfl_xor(dlane, 8,  64);
  dlane += __shfl_xor(dlane, 16, 64);
  dlane += __shfl_xor(dlane, 32, 64);
  const float denom = __shfl(dlane, hd, 64);

  const float inv = 1.f / (denom + 1e-8f);
  const float2 x = reinterpret_cast<const float2*>(X + (size_t)n * D_MODEL)[l];
  const float a0 = accx * inv + x.x;
  const float a1 = accy * inv + x.y;

  float sm = a0 + a1;
  float ss = a0 * a0 + a1 * a1;
  #pragma unroll
  for (int off = 32; off > 0; off >>= 1) {
    sm += __shfl_xor(sm, off, 64);
    ss += __shfl_xor(ss, off, 64);
  }
  const float mean = sm * (1.f / 128.f);
  const float var  = ss * (1.f / 128.f) - mean * mean;
  const float rs   = rsqrtf(var + 1e-6f);
  const float2 gm = reinterpret_cast<const float2*>(gamma)[l];
  const float2 bt = reinterpret_cast<const float2*>(beta)[l];
  float2 o;
  o.x = (a0 - mean) * rs * gm.x + bt.x;
  o.y = (a1 - mean) * rs * gm.y + bt.y;
  reinterpret_cast<float2*>(out + (size_t)n * D_MODEL)[l] = o;
}

// ---------------------------------------------------------------------------
extern "C" void kernel_launch(void* const* d_in, const int* in_sizes, int n_in,
                              void* d_out, int out_size, void* d_ws, size_t ws_size,
                              hipStream_t stream)
{
  const float* X     = (const float*)d_in[0];
  const int*   ei    = (const int*)  d_in[1];
  const float* Wq    = (const float*)d_in[2];
  const float* bq    = (const float*)d_in[3];
  const float* Wk    = (const float*)d_in[4];
  const float* bk    = (const float*)d_in[5];
  const float* Wv    = (const float*)d_in[6];
  const float* bv    = (const float*)d_in[7];
  const float* gamma = (const float*)d_in[8];
  const float* beta  = (const float*)d_in[9];

  const int N = in_sizes[0] / D_MODEL;
  const int E = in_sizes[1] / 2;
  const int* rows = ei;
  const int* cols = ei + E;

  const size_t nd = (size_t)N * D_MODEL;
  unsigned short* Wb = (unsigned short*)d_ws;
  unsigned short* Qb = Wb + 3 * 16384;
  unsigned short* Kb = Qb + nd;
  unsigned short* Vb = Kb + nd;
  int* row_cnt  = (int*)(Vb + nd);
  int* row_ptr  = row_cnt + N;
  int* row_cur  = row_ptr + N + 1;
  int* csr_cols = row_cur + N;
  int* bsum     = csr_cols + E;
  int* boff     = bsum + ((N + 1023) / 1024) + 1;

  const int nb = (N + 1023) / 1024;

  hipMemsetAsync(row_cnt, 0, (size_t)N * sizeof(int), stream);

  cvtw_kernel<<<24, 256, 0, stream>>>(Wq, Wk, Wv, Wb);

  hist_kernel<<<(E + 255) / 256, 256, 0, stream>>>(rows, row_cnt, E);
  partial_kernel<<<nb, 256, 0, stream>>>(row_cnt, bsum, N);
  scansums_kernel<<<1, 256, 0, stream>>>(bsum, boff, nb);
  emit_kernel<<<nb, 256, 0, stream>>>(row_cnt, boff, row_ptr, row_cur, N, E);
  scatter_kernel<<<(E + 255) / 256, 256, 0, stream>>>(rows, cols, row_cur, csr_cols, E);

  qkv_mfma<<<(N + 63) / 64, 128, 0, stream>>>(
      X, Wb, bq, bk, bv, Qb, Kb, Vb, N);

  fused_kernel<<<(N + 3) / 4, 256, 0, stream>>>(
      Qb, Kb, Vb, X, row_ptr, csr_cols, gamma, beta, (float*)d_out, N);
}